// Round 3
// baseline (549.610 us; speedup 1.0000x reference)
//
#include <hip/hip_runtime.h>
#include <hip/hip_bf16.h>

#pragma clang fp contract(off)

typedef __attribute__((ext_vector_type(4))) float f32x4;

// ---------------------------------------------------------------------------
// Transpose (2*C_half, HW) channel-major f32 (two source arrays e,g) into
// (HW, CC) position-major f32: dst[pos*CC + c], c<CC/2 = e-ch, else g-ch.
// LDS-tiled, coalesced both sides, odd LDS stride -> <=2-way banks (free).
// ---------------------------------------------------------------------------
template<int CC, int TP>
__global__ __launch_bounds__(256) void transpose_pair(
    const float* __restrict__ e, const float* __restrict__ g,
    float* __restrict__ dst, int HW)
{
    __shared__ float tile[CC][TP + 1];
    const int tbase = blockIdx.x * TP;
    const int t = threadIdx.x;
    constexpr int ITER = CC * TP / 256;
#pragma unroll
    for (int i = 0; i < ITER; ++i) {
        int eidx = i * 256 + t;
        int c  = eidx / TP;
        int pl = eidx % TP;
        const float* src = (c < CC / 2) ? e : g;
        int cs = (c < CC / 2) ? c : (c - CC / 2);
        tile[c][pl] = src[(size_t)cs * HW + tbase + pl];
    }
    __syncthreads();
#pragma unroll
    for (int i = 0; i < ITER; ++i) {
        int eidx = i * 256 + t;
        int pl = eidx / CC;
        int c  = eidx % CC;
        dst[(size_t)(tbase + pl) * CC + c] = tile[c][pl];
    }
}

// ---------------------------------------------------------------------------
// Plane sampler, transposed layout, bit-exact f32 interpolation order
// ---------------------------------------------------------------------------
__device__ __forceinline__ float sample_plane_pair_T(
    const float* __restrict__ tp, float gx, float gy)
{
    float ix = fminf(fmaxf((gx + 1.0f) * 0.5f * 127.0f, 0.0f), 127.0f);
    float iy = fminf(fmaxf((gy + 1.0f) * 0.5f * 127.0f, 0.0f), 127.0f);
    float x0f = floorf(ix), y0f = floorf(iy);
    float wx = ix - x0f, wy = iy - y0f;
    int x0 = (int)x0f, y0 = (int)y0f;
    int x1 = x0 + 1, y1 = y0 + 1;
    float vx1 = (x1 < 128) ? 1.0f : 0.0f;
    float vy1 = (y1 < 128) ? 1.0f : 0.0f;
    int x1c = min(x1, 127), y1c = min(y1, 127);
    float omwx = 1.0f - wx, omwy = 1.0f - wy;
    float w00 = omwx * omwy;
    float w10 = (wx * omwy) * vx1;
    float w01 = (omwx * wy) * vy1;
    float w11 = ((wx * wy) * vx1) * vy1;
    const float* b00 = tp + (((size_t)y0  * 128 + x0 ) << 6);
    const float* b10 = tp + (((size_t)y0  * 128 + x1c) << 6);
    const float* b01 = tp + (((size_t)y1c * 128 + x0 ) << 6);
    const float* b11 = tp + (((size_t)y1c * 128 + x1c) << 6);
    float acc = 0.0f;
#pragma unroll
    for (int cc = 0; cc < 32; cc += 4) {
        f32x4 e00 = *(const f32x4*)(b00 + cc);
        f32x4 e10 = *(const f32x4*)(b10 + cc);
        f32x4 e01 = *(const f32x4*)(b01 + cc);
        f32x4 e11 = *(const f32x4*)(b11 + cc);
        f32x4 g00 = *(const f32x4*)(b00 + 32 + cc);
        f32x4 g10 = *(const f32x4*)(b10 + 32 + cc);
        f32x4 g01 = *(const f32x4*)(b01 + 32 + cc);
        f32x4 g11 = *(const f32x4*)(b11 + 32 + cc);
#pragma unroll
        for (int j = 0; j < 4; ++j) {
            float ei = ((e00[j] * w00 + e10[j] * w10) + e01[j] * w01) + e11[j] * w11;
            float gi = ((g00[j] * w00 + g10[j] * w10) + g01[j] * w01) + g11[j] * w11;
            acc += (gi >= 0.0f) ? ei : 0.0f;
        }
    }
    return acc;
}

// ---------------------------------------------------------------------------
// Volume sampler, transposed layout, ref tt order (dz major), w=(fx*fy)*fz
// ---------------------------------------------------------------------------
__device__ __forceinline__ float sample_volume_T(
    const float* __restrict__ tv, float gx, float gy, float gz)
{
    float ix = fminf(fmaxf((gx + 1.0f) * 0.5f * 63.0f, 0.0f), 63.0f);
    float iy = fminf(fmaxf((gy + 1.0f) * 0.5f * 63.0f, 0.0f), 63.0f);
    float iz = fminf(fmaxf((gz + 1.0f) * 0.5f * 63.0f, 0.0f), 63.0f);
    float x0f = floorf(ix), y0f = floorf(iy), z0f = floorf(iz);
    float wx = ix - x0f, wy = iy - y0f, wz = iz - z0f;
    int x0 = (int)x0f, y0 = (int)y0f, z0 = (int)z0f;
    int x1 = x0 + 1, y1 = y0 + 1, z1 = z0 + 1;
    float fx[2] = {1.0f - wx, wx}, fy[2] = {1.0f - wy, wy}, fz[2] = {1.0f - wz, wz};
    float vx[2] = {1.0f, (x1 < 64) ? 1.0f : 0.0f};
    float vy[2] = {1.0f, (y1 < 64) ? 1.0f : 0.0f};
    float vz[2] = {1.0f, (z1 < 64) ? 1.0f : 0.0f};
    int xi[2] = {x0, min(x1, 63)}, yi[2] = {y0, min(y1, 63)}, zi[2] = {z0, min(z1, 63)};

    const float* bp[8];
    float w[8];
#pragma unroll
    for (int dz = 0; dz < 2; ++dz)
#pragma unroll
        for (int dy = 0; dy < 2; ++dy)
#pragma unroll
            for (int dx = 0; dx < 2; ++dx) {
                int tt = (dz << 2) | (dy << 1) | dx;   // reference add order
                w[tt] = (((fx[dx] * fy[dy]) * fz[dz]) * vx[dx]) * (vy[dy] * vz[dz]);
                bp[tt] = tv + (((size_t)(zi[dz] * 64 + yi[dy]) * 64 + xi[dx]) << 5);
            }
    float acc = 0.0f;
#pragma unroll
    for (int cc = 0; cc < 16; cc += 4) {
        f32x4 eacc = {0.0f, 0.0f, 0.0f, 0.0f};
        f32x4 gacc = {0.0f, 0.0f, 0.0f, 0.0f};
#pragma unroll
        for (int tt = 0; tt < 8; ++tt) {
            f32x4 ev = *(const f32x4*)(bp[tt] + cc);
            f32x4 gv = *(const f32x4*)(bp[tt] + 16 + cc);
#pragma unroll
            for (int j = 0; j < 4; ++j) {
                eacc[j] = eacc[j] + ev[j] * w[tt];
                gacc[j] = gacc[j] + gv[j] * w[tt];
            }
        }
#pragma unroll
        for (int j = 0; j < 4; ++j)
            acc += (gacc[j] >= 0.0f) ? eacc[j] : 0.0f;
    }
    return acc;
}

// ---------------------------------------------------------------------------
// Line term: constant across points (W=1 -> ix=0 wx=0; gy=0 -> iy=63.5)
// ---------------------------------------------------------------------------
__device__ __forceinline__ float line_pair(const float* __restrict__ e,
                                           const float* __restrict__ g, int c)
{
    float ev = e[c * 128 + 63] * 0.5f + e[c * 128 + 64] * 0.5f;
    float gv = g[c * 128 + 63] * 0.5f + g[c * 128 + 64] * 0.5f;
    return (gv >= 0.0f) ? ev : 0.0f;
}

__device__ __forceinline__ float block_line_const(
    const float* lx, const float* ly, const float* lz,
    const float* lxg, const float* lyg, const float* lzg)
{
    __shared__ float lc_sh;
    int t = threadIdx.x;
    if (t < 64) {
        float part = line_pair(lx, lxg, t) + line_pair(ly, lyg, t) + line_pair(lz, lzg, t);
#pragma unroll
        for (int off = 32; off > 0; off >>= 1) part += __shfl_down(part, off);
        if (t == 0) lc_sh = part;
    }
    __syncthreads();
    return lc_sh;
}

// ---------------------------------------------------------------------------
// Main kernel (transposed f32 tables)
// ---------------------------------------------------------------------------
__global__ __launch_bounds__(256) void ctri_main_T(
    const float* __restrict__ coords,
    const float* __restrict__ lx,  const float* __restrict__ ly,  const float* __restrict__ lz,
    const float* __restrict__ lxg, const float* __restrict__ lyg, const float* __restrict__ lzg,
    const float* __restrict__ tpxy, const float* __restrict__ tpyz, const float* __restrict__ tpxz,
    const float* __restrict__ tv,
    float* __restrict__ out, int P)
{
    float lc = block_line_const(lx, ly, lz, lxg, lyg, lzg);
    int p = blockIdx.x * blockDim.x + threadIdx.x;
    if (p >= P) return;
    float x = coords[3 * p + 0];
    float y = coords[3 * p + 1];
    float z = coords[3 * p + 2];
    float acc = lc;
    acc += sample_plane_pair_T(tpxy, x, y);
    acc += sample_plane_pair_T(tpyz, y, z);
    acc += sample_plane_pair_T(tpxz, x, z);
    acc += sample_volume_T(tv, x, y, z);
    out[p] = acc;
}

// ---------------------------------------------------------------------------
// Direct-layout f32 fallback (used only if ws_size too small)
// ---------------------------------------------------------------------------
__device__ __forceinline__ float sample_plane_pair_D(
    const float* __restrict__ e, const float* __restrict__ g, float gx, float gy)
{
    float ix = fminf(fmaxf((gx + 1.0f) * 0.5f * 127.0f, 0.0f), 127.0f);
    float iy = fminf(fmaxf((gy + 1.0f) * 0.5f * 127.0f, 0.0f), 127.0f);
    float x0f = floorf(ix), y0f = floorf(iy);
    float wx = ix - x0f, wy = iy - y0f;
    int x0 = (int)x0f, y0 = (int)y0f;
    int x1 = x0 + 1, y1 = y0 + 1;
    float vx1 = (x1 < 128) ? 1.0f : 0.0f;
    float vy1 = (y1 < 128) ? 1.0f : 0.0f;
    int x1c = min(x1, 127), y1c = min(y1, 127);
    float omwx = 1.0f - wx, omwy = 1.0f - wy;
    float w00 = omwx * omwy;
    float w10 = (wx * omwy) * vx1;
    float w01 = (omwx * wy) * vy1;
    float w11 = ((wx * wy) * vx1) * vy1;
    int o00 = y0 * 128 + x0, o10 = y0 * 128 + x1c;
    int o01 = y1c * 128 + x0, o11 = y1c * 128 + x1c;
    float acc = 0.0f;
#pragma unroll 4
    for (int c = 0; c < 32; ++c) {
        const float* ec = e + (size_t)c * 16384;
        const float* gc = g + (size_t)c * 16384;
        float ei = ((ec[o00] * w00 + ec[o10] * w10) + ec[o01] * w01) + ec[o11] * w11;
        float gi = ((gc[o00] * w00 + gc[o10] * w10) + gc[o01] * w01) + gc[o11] * w11;
        acc += (gi >= 0.0f) ? ei : 0.0f;
    }
    return acc;
}

__device__ __forceinline__ float sample_volume_D(
    const float* __restrict__ e, const float* __restrict__ g,
    float gx, float gy, float gz)
{
    float ix = fminf(fmaxf((gx + 1.0f) * 0.5f * 63.0f, 0.0f), 63.0f);
    float iy = fminf(fmaxf((gy + 1.0f) * 0.5f * 63.0f, 0.0f), 63.0f);
    float iz = fminf(fmaxf((gz + 1.0f) * 0.5f * 63.0f, 0.0f), 63.0f);
    float x0f = floorf(ix), y0f = floorf(iy), z0f = floorf(iz);
    float wx = ix - x0f, wy = iy - y0f, wz = iz - z0f;
    int x0 = (int)x0f, y0 = (int)y0f, z0 = (int)z0f;
    int x1 = x0 + 1, y1 = y0 + 1, z1 = z0 + 1;
    float fx[2] = {1.0f - wx, wx}, fy[2] = {1.0f - wy, wy}, fz[2] = {1.0f - wz, wz};
    float vx[2] = {1.0f, (x1 < 64) ? 1.0f : 0.0f};
    float vy[2] = {1.0f, (y1 < 64) ? 1.0f : 0.0f};
    float vz[2] = {1.0f, (z1 < 64) ? 1.0f : 0.0f};
    int xi[2] = {x0, min(x1, 63)}, yi[2] = {y0, min(y1, 63)}, zi[2] = {z0, min(z1, 63)};
    int o[8]; float w[8];
#pragma unroll
    for (int dz = 0; dz < 2; ++dz)
#pragma unroll
        for (int dy = 0; dy < 2; ++dy)
#pragma unroll
            for (int dx = 0; dx < 2; ++dx) {
                int tt = (dz << 2) | (dy << 1) | dx;
                w[tt] = (((fx[dx] * fy[dy]) * fz[dz]) * vx[dx]) * (vy[dy] * vz[dz]);
                o[tt] = (zi[dz] * 64 + yi[dy]) * 64 + xi[dx];
            }
    float acc = 0.0f;
#pragma unroll 2
    for (int c = 0; c < 16; ++c) {
        const float* ec = e + (size_t)c * 262144;
        const float* gc = g + (size_t)c * 262144;
        float ei = 0.0f, gi = 0.0f;
#pragma unroll
        for (int tt = 0; tt < 8; ++tt) {
            ei = ei + ec[o[tt]] * w[tt];
            gi = gi + gc[o[tt]] * w[tt];
        }
        acc += (gi >= 0.0f) ? ei : 0.0f;
    }
    return acc;
}

__global__ __launch_bounds__(256) void ctri_main_D(
    const float* __restrict__ coords,
    const float* __restrict__ lx,  const float* __restrict__ ly,  const float* __restrict__ lz,
    const float* __restrict__ lxg, const float* __restrict__ lyg, const float* __restrict__ lzg,
    const float* __restrict__ pxy, const float* __restrict__ pyz, const float* __restrict__ pxz,
    const float* __restrict__ pxyg, const float* __restrict__ pyzg, const float* __restrict__ pxzg,
    const float* __restrict__ vol, const float* __restrict__ volg,
    float* __restrict__ out, int P)
{
    float lc = block_line_const(lx, ly, lz, lxg, lyg, lzg);
    int p = blockIdx.x * blockDim.x + threadIdx.x;
    if (p >= P) return;
    float x = coords[3 * p + 0];
    float y = coords[3 * p + 1];
    float z = coords[3 * p + 2];
    float acc = lc;
    acc += sample_plane_pair_D(pxy, pxyg, x, y);
    acc += sample_plane_pair_D(pyz, pyzg, y, z);
    acc += sample_plane_pair_D(pxz, pxzg, x, z);
    acc += sample_volume_D(vol, volg, x, y, z);
    out[p] = acc;
}

// ---------------------------------------------------------------------------
extern "C" void kernel_launch(void* const* d_in, const int* in_sizes, int n_in,
                              void* d_out, int out_size, void* d_ws, size_t ws_size,
                              hipStream_t stream)
{
    (void)n_in; (void)out_size;
    const float* coords = (const float*)d_in[0];
    const float* pxy  = (const float*)d_in[1];
    const float* pyz  = (const float*)d_in[2];
    const float* pxz  = (const float*)d_in[3];
    const float* pxyg = (const float*)d_in[4];
    const float* pyzg = (const float*)d_in[5];
    const float* pxzg = (const float*)d_in[6];
    const float* lx   = (const float*)d_in[7];
    const float* ly   = (const float*)d_in[8];
    const float* lz   = (const float*)d_in[9];
    const float* lxg  = (const float*)d_in[10];
    const float* lyg  = (const float*)d_in[11];
    const float* lzg  = (const float*)d_in[12];
    const float* vol  = (const float*)d_in[13];
    const float* volg = (const float*)d_in[14];
    float* out = (float*)d_out;

    const int P = in_sizes[0] / 3;                       // 262144
    const size_t planeT_elems = (size_t)16384 * 64;      // f32
    const size_t volT_elems   = (size_t)262144 * 32;     // f32
    const size_t need_bytes   = (3 * planeT_elems + volT_elems) * sizeof(float);

    const int blocks = (P + 255) / 256;
    if (ws_size >= need_bytes) {
        float* tpxy = (float*)d_ws;
        float* tpyz = tpxy + planeT_elems;
        float* tpxz = tpyz + planeT_elems;
        float* tv   = tpxz + planeT_elems;
        transpose_pair<64, 64><<<256, 256, 0, stream>>>(pxy, pxyg, tpxy, 16384);
        transpose_pair<64, 64><<<256, 256, 0, stream>>>(pyz, pyzg, tpyz, 16384);
        transpose_pair<64, 64><<<256, 256, 0, stream>>>(pxz, pxzg, tpxz, 16384);
        transpose_pair<32, 128><<<2048, 256, 0, stream>>>(vol, volg, tv, 262144);
        ctri_main_T<<<blocks, 256, 0, stream>>>(coords, lx, ly, lz, lxg, lyg, lzg,
                                                tpxy, tpyz, tpxz, tv, out, P);
    } else {
        ctri_main_D<<<blocks, 256, 0, stream>>>(coords, lx, ly, lz, lxg, lyg, lzg,
                                                pxy, pyz, pxz, pxyg, pyzg, pxzg,
                                                vol, volg, out, P);
    }
}